// Round 1
// baseline (91.502 us; speedup 1.0000x reference)
//
#include <hip/hip_runtime.h>
#include <cstddef>
#include <cstdint>

// EdgeSheafLaplacian: n=1024 nodes, stalk d=8, P=32768 directed edges.
// Output Delta (8192 x 8192) f32, dense but block-sparse in content:
// 1024 diagonal blocks + P edge blocks nonzero; everything else zero.
//
// Pipeline:
//   memset out=0, Mmap=-1, diag=0
//   K1: per-edge FtF = R^T R (wave shuffles), atomicAdd into diag[i]; Mmap[i,j]=p
//   K2: per-node D = sym(diag)+eps*I; Dis = D^{-1/2} via Newton-Schulz
//       (valid: D = sum of Wisharts + eps*I, lambda_min >> eps, so the
//        reference's clip(w, EPS) is inactive and D^{-1/2} is smooth)
//   K3: per nonzero block: M = -sgn * R_ji^T R_ij (or diag[v]); out = Dis_i M Dis_j

namespace {
constexpr int N = 1024;     // nodes (N_EDGES in the reference's naming)
constexpr int Dd = 8;       // stalk dim
constexpr int ND = N * Dd;  // 8192
}

__global__ void k_build(const float* __restrict__ R, const int* __restrict__ eidx,
                        int P, int* __restrict__ Mmap, float* __restrict__ diag) {
  int gid = blockIdx.x * blockDim.x + threadIdx.x;
  int u = gid >> 6;
  if (u >= P) return;
  int lane = gid & 63;
  int a = lane >> 3, b = lane & 7;
  int i = eidx[2 * u];
  int j = eidx[2 * u + 1];
  float r = R[(size_t)u * 64 + lane];
  // FtF[a][b] = sum_k R[k][a] * R[k][b]
  float acc = 0.f;
#pragma unroll
  for (int k = 0; k < 8; ++k)
    acc += __shfl(r, k * 8 + a, 64) * __shfl(r, k * 8 + b, 64);
  atomicAdd(&diag[i * 64 + lane], acc);
  if (lane == 0 && Mmap) Mmap[i * N + j] = u;
}

__global__ void k_invsqrt(const float* __restrict__ diag, float* __restrict__ Dis) {
  int gid = blockIdx.x * blockDim.x + threadIdx.x;
  int v = gid >> 6;
  if (v >= N) return;
  int lane = gid & 63;
  int a = lane >> 3, b = lane & 7;
  float dv = diag[v * 64 + lane];
  float dvt = __shfl(dv, b * 8 + a, 64);
  float A = 0.5f * (dv + dvt) + (a == b ? 1e-4f : 0.f);
  // Frobenius norm across the wave (64 elements)
  float sq = A * A;
#pragma unroll
  for (int off = 32; off; off >>= 1) sq += __shfl_xor(sq, off, 64);
  float fro = sqrtf(sq);
  float s = 1.f / fro;
  // Newton-Schulz coupled iteration on Y0 = A/fro (spectrum in (0,1]), Z0 = I.
  // Z_k -> (A/fro)^{-1/2}; 18 iters is overkill-converged even for
  // lambda_norm ~ 1e-3 (growth ~2.25x/iter then quadratic).
  float Y = A * s;
  float Z = (a == b) ? 1.f : 0.f;
  for (int it = 0; it < 18; ++it) {
    float T = 0.f;
#pragma unroll
    for (int k = 0; k < 8; ++k)
      T += __shfl(Z, a * 8 + k, 64) * __shfl(Y, k * 8 + b, 64);
    float G = ((a == b) ? 1.5f : 0.f) - 0.5f * T;  // (3I - ZY)/2
    float Yn = 0.f, Zn = 0.f;
#pragma unroll
    for (int k = 0; k < 8; ++k) {
      Yn += __shfl(Y, a * 8 + k, 64) * __shfl(G, k * 8 + b, 64);
      Zn += __shfl(G, a * 8 + k, 64) * __shfl(Z, k * 8 + b, 64);
    }
    Y = Yn;
    Z = Zn;
  }
  // D^{-1/2} = (fro * Anorm)^{-1/2} = Z / sqrt(fro)
  Dis[v * 64 + lane] = Z * (1.f / sqrtf(fro));
}

__global__ void k_blocks(const float* __restrict__ R, const int* __restrict__ eidx,
                         const float* __restrict__ L1, const int* __restrict__ Mmap,
                         const float* __restrict__ diag, const float* __restrict__ Dis,
                         int P, float* __restrict__ out) {
  int gid = blockIdx.x * blockDim.x + threadIdx.x;
  int u = gid >> 6;
  if (u >= P + N) return;
  int lane = gid & 63;
  int a = lane >> 3, b = lane & 7;
  int i, j;
  float M;
  if (u < P) {
    int p = u;
    i = eidx[2 * p];
    j = eidx[2 * p + 1];
    int rev;
    if (Mmap) {
      rev = Mmap[j * N + i];
    } else {
      // structural fallback: directed = [ [lo,hi] ; [hi,lo] ]
      rev = (p < P / 2) ? p + P / 2 : p - P / 2;
      if (eidx[2 * rev] != j || eidx[2 * rev + 1] != i) rev = -1;
    }
    float l1v = L1[i * N + j];
    float sgn = (l1v > 0.f ? 1.f : 0.f) - (l1v < 0.f ? 1.f : 0.f);
    if (rev < 0 || sgn == 0.f) return;  // block stays zero (memset) — wave-uniform
    float rp = R[(size_t)p * 64 + lane];
    float rr = R[(size_t)rev * 64 + lane];
    float m = 0.f;
#pragma unroll
    for (int k = 0; k < 8; ++k)
      m += __shfl(rr, k * 8 + a, 64) * __shfl(rp, k * 8 + b, 64);
    M = -sgn * m;
  } else {
    int v = u - P;
    i = v;
    j = v;
    M = diag[v * 64 + lane];
  }
  float di = Dis[i * 64 + lane];
  float dj = Dis[j * 64 + lane];
  // T = M * Dis_j ; out = Dis_i * T
  float T = 0.f;
#pragma unroll
  for (int k = 0; k < 8; ++k)
    T += __shfl(M, a * 8 + k, 64) * __shfl(dj, k * 8 + b, 64);
  float o = 0.f;
#pragma unroll
  for (int k = 0; k < 8; ++k)
    o += __shfl(di, a * 8 + k, 64) * __shfl(T, k * 8 + b, 64);
  out[(size_t)(i * Dd + a) * ND + (j * Dd + b)] = o;
}

extern "C" void kernel_launch(void* const* d_in, const int* in_sizes, int n_in,
                              void* d_out, int out_size, void* d_ws, size_t ws_size,
                              hipStream_t stream) {
  const float* R = (const float*)d_in[0];
  const int* eidx = (const int*)d_in[1];
  // d_in[2] = num_edges (device scalar) — statically 1024 per setup_inputs
  const float* L1 = (const float*)d_in[3];
  float* out = (float*)d_out;
  int P = in_sizes[0] / 64;  // 32768

  size_t mmapBytes = (size_t)N * N * sizeof(int);     // 4 MiB
  size_t diagBytes = (size_t)N * 64 * sizeof(float);  // 256 KiB
  int* Mmap = nullptr;
  float* diag;
  float* Dis;
  if (ws_size >= mmapBytes + 2 * diagBytes) {
    Mmap = (int*)d_ws;
    diag = (float*)((char*)d_ws + mmapBytes);
    Dis = (float*)((char*)d_ws + mmapBytes + diagBytes);
    hipMemsetAsync(Mmap, 0xFF, mmapBytes, stream);  // -1
  } else {
    diag = (float*)d_ws;
    Dis = (float*)((char*)d_ws + diagBytes);
  }
  hipMemsetAsync(diag, 0, diagBytes, stream);
  hipMemsetAsync(out, 0, (size_t)out_size * sizeof(float), stream);

  {
    long threads = (long)P * 64;
    k_build<<<(int)((threads + 255) / 256), 256, 0, stream>>>(R, eidx, P, Mmap, diag);
  }
  k_invsqrt<<<(N * 64) / 256, 256, 0, stream>>>(diag, Dis);
  {
    long threads = (long)(P + N) * 64;
    k_blocks<<<(int)((threads + 255) / 256), 256, 0, stream>>>(R, eidx, L1, Mmap, diag,
                                                               Dis, P, out);
  }
}